// Round 4
// baseline (498.985 us; speedup 1.0000x reference)
//
#include <hip/hip_runtime.h>

#define B_ 2048
#define F_ 64
#define DRAW_ 32
#define D_ 15
#define ROWS_ (B_*F_)     /* 131072 rows = (b,f) */
#define BD_ (B_*D_)       /* 30720 rows = (b,d) */

// ---------------------------------------------------------------------------
// k_prep: v[f][k] = sum_j W2[k][j]*dw[114+f*32+j];  C = sum_{f,j} bout[j]*dw[114+f*32+j]
// ---------------------------------------------------------------------------
__global__ __launch_bounds__(256)
void k_prep(const float* __restrict__ W2,      // [128][32]
            const float* __restrict__ bout,    // [32]
            const float* __restrict__ dw,      // [2162]
            float* __restrict__ v,             // [64][128]
            float* __restrict__ Cout) {        // [1]
    int tid = threadIdx.x;
    for (int idx = tid; idx < 64*128; idx += 256) {
        int f = idx >> 7, k = idx & 127;
        float s = 0.f;
        #pragma unroll
        for (int j = 0; j < 32; ++j) s += W2[k*32+j] * dw[114 + f*32 + j];
        v[idx] = s;
    }
    float p = 0.f;
    for (int idx = tid; idx < 2048; idx += 256)
        p += bout[idx & 31] * dw[114 + idx];
    __shared__ float red[256];
    red[tid] = p;
    __syncthreads();
    for (int s = 128; s > 0; s >>= 1) {
        if (tid < s) red[tid] += red[tid+s];
        __syncthreads();
    }
    if (tid == 0) Cout[0] = red[0];
}

// ---------------------------------------------------------------------------
// k_emb: emb = x@embW + embB (stored in both [b,f,d] and [b,d,f] layouts);
//        liner[row] = x@linW + linB
// ---------------------------------------------------------------------------
__global__ __launch_bounds__(256)
void k_emb(const float* __restrict__ x,        // [B,F,32]
           const float* __restrict__ embW,     // [32][15]
           const float* __restrict__ embB,     // [15]
           const float* __restrict__ linW,     // [32]
           const float* __restrict__ linB,     // [1]
           float* __restrict__ emb_bfd,        // [ROWS][15]
           float* __restrict__ emb_bdf,        // [BD][64]
           float* __restrict__ liner) {        // [ROWS]
    __shared__ float xL[256*33];   // 33.8 KB
    __shared__ float wL[32*15];
    __shared__ float lwL[32];
    int tid = threadIdx.x;
    for (int i = tid; i < 480; i += 256) wL[i] = embW[i];
    if (tid < 32) lwL[tid] = linW[tid];
    // coalesced stage of 256 rows x 32 floats (pad 33 -> conflict-free reads)
    const float4* xs = (const float4*)(x + (size_t)blockIdx.x * 256 * 32);
    #pragma unroll
    for (int j = 0; j < 8; ++j) {
        int f4 = tid + 256*j;
        float4 val = xs[f4];
        int row = f4 >> 3, k0 = (f4 & 7) << 2;
        xL[row*33 + k0]     = val.x;
        xL[row*33 + k0 + 1] = val.y;
        xL[row*33 + k0 + 2] = val.z;
        xL[row*33 + k0 + 3] = val.w;
    }
    __syncthreads();
    int row = blockIdx.x * 256 + tid;
    float acc[15];
    #pragma unroll
    for (int d2 = 0; d2 < 15; ++d2) acc[d2] = 0.f;
    float lin = 0.f;
    #pragma unroll
    for (int k = 0; k < 32; ++k) {
        float xv = xL[tid*33 + k];
        #pragma unroll
        for (int d2 = 0; d2 < 15; ++d2) acc[d2] += xv * wL[k*15 + d2];
        lin += xv * lwL[k];
    }
    int b = row >> 6, f = row & 63;
    #pragma unroll
    for (int d2 = 0; d2 < 15; ++d2) {
        float val = acc[d2] + embB[d2];
        emb_bfd[(size_t)row*15 + d2] = val;
        emb_bdf[(size_t)(b*15 + d2)*64 + f] = val;   // coalesced over f within wave
    }
    liner[row] = lin + linB[0];
}

// ---------------------------------------------------------------------------
// k_dnn: fused  h1=relu(emb@W0+b0) -> h2=relu(h1@W1+b1) -> rdnn=h2 . v[f]
// 128 rows/block, 256 threads, 8x8 register tile, W1 chunk-staged.
// h1 (134 MB if materialized) is recomputed in-block: +12% FLOPs, -45 µs HBM.
// ---------------------------------------------------------------------------
__global__ __launch_bounds__(256)
void k_dnn(const float* __restrict__ emb_bfd,  // [ROWS][15]
           const float* __restrict__ W0,       // [15][256]
           const float* __restrict__ b0,       // [256]
           const float* __restrict__ W1,       // [256][128]
           const float* __restrict__ b1,       // [128]
           const float* __restrict__ v,        // [64][128]
           float* __restrict__ rdnn) {         // [ROWS]
    __shared__ float embL[128*16];
    __shared__ float w0L[15*256];
    __shared__ float h1L[128*33];   // chunk of 32 h1-cols, pad 33
    __shared__ float w1L[32*130];   // chunk of 32 W1-rows, pad 130
    int tid = threadIdx.x;
    int rows0 = blockIdx.x * 128;

    for (int i = tid; i < 128*15; i += 256) {
        int r = i / 15, q = i - r*15;
        embL[r*16+q] = emb_bfd[(size_t)rows0*15 + i];
    }
    for (int i = tid; i < 15*256; i += 256) w0L[i] = W0[i];
    __syncthreads();

    float acc[8][8];
    #pragma unroll
    for (int i = 0; i < 8; ++i)
        #pragma unroll
        for (int j = 0; j < 8; ++j) acc[i][j] = 0.f;

    int c2 = tid & 31, rg = tid >> 5;   // layer-1 compute map
    int ct = tid & 15, rt = tid >> 4;   // GEMM map: rows rt*8..+7, cols ct+16*j

    for (int kc = 0; kc < 8; ++kc) {
        // stage W1 chunk (coalesced)
        for (int i = tid; i < 4096; i += 256) {
            int k = i >> 7, c = i & 127;
            w1L[k*130 + c] = W1[kc*4096 + i];
        }
        // compute h1 chunk: each thread = 1 col (c2), 16 rows
        float bb = b0[kc*32 + c2];
        #pragma unroll
        for (int r16 = 0; r16 < 16; ++r16) {
            int r = rg*16 + r16;
            float s = bb;
            #pragma unroll
            for (int q = 0; q < 15; ++q)
                s += embL[r*16+q] * w0L[q*256 + kc*32 + c2];
            h1L[r*33 + c2] = fmaxf(s, 0.f);
        }
        __syncthreads();
        // GEMM: 32 k-steps, 8x8 tile; a: 4 banks x16-bcast, w: 16 banks x4-bcast
        #pragma unroll 4
        for (int k = 0; k < 32; ++k) {
            float a[8], w[8];
            #pragma unroll
            for (int i = 0; i < 8; ++i) a[i] = h1L[(rt*8+i)*33 + k];
            #pragma unroll
            for (int j = 0; j < 8; ++j) w[j] = w1L[k*130 + ct + 16*j];
            #pragma unroll
            for (int i = 0; i < 8; ++i)
                #pragma unroll
                for (int j = 0; j < 8; ++j) acc[i][j] += a[i]*w[j];
        }
        __syncthreads();
    }
    // epilogue: relu(+b1) then dot with v[f], reduce across 16 col-threads
    float b1v[8];
    #pragma unroll
    for (int j = 0; j < 8; ++j) b1v[j] = b1[ct + 16*j];
    #pragma unroll
    for (int i = 0; i < 8; ++i) {
        int lrow = rt*8 + i;
        int f = (rows0 + lrow) & 63;
        float p = 0.f;
        #pragma unroll
        for (int j = 0; j < 8; ++j) {
            float h2 = fmaxf(acc[i][j] + b1v[j], 0.f);
            p += h2 * v[f*128 + ct + 16*j];
        }
        p += __shfl_xor(p, 1, 64);
        p += __shfl_xor(p, 2, 64);
        p += __shfl_xor(p, 4, 64);
        p += __shfl_xor(p, 8, 64);
        if (ct == 0) rdnn[rows0 + lrow] = p;
    }
}

// ---------------------------------------------------------------------------
// k_cin: full CIN (5 layers) — rows are (b,d) pairs, fully independent.
// Layer l: T[row,f*10+n] = sum_g h[row,g]*A_l[g,f*10+n];  A_l reindexes W_l.
//          h_next[row,n] = sum_f E[row,f]*T[row,f*10+n].
// 32 rows/block, 256 threads, 4x20 register tile (cols ct*20..+19 = fields 2ct,2ct+1)
// ---------------------------------------------------------------------------
__global__ __launch_bounds__(256)
void k_cin(const float* __restrict__ emb_bdf,  // [BD][64]
           const float* __restrict__ cw0,      // [4096][10]
           const float* __restrict__ cw1,      // [640][10]
           const float* __restrict__ cw2,
           const float* __restrict__ cw3,
           const float* __restrict__ cw4,
           float* __restrict__ hi_ws) {        // [5][BD][10]
    __shared__ float EL[32*65];
    __shared__ float AL[16*648];
    __shared__ float hL[32*13];
    int tid = threadIdx.x;
    int rows0 = blockIdx.x * 32;

    for (int i = tid; i < 32*64; i += 256) {
        int r = i >> 6, g = i & 63;
        EL[r*65+g] = emb_bdf[(size_t)rows0*64 + i];
    }
    int ct = tid & 31, rt = tid >> 5;   // rows rt*4..+3, cols ct*20..+19
    float acc[4][20];
    #pragma unroll
    for (int i = 0; i < 4; ++i)
        #pragma unroll
        for (int j = 0; j < 20; ++j) acc[i][j] = 0.f;

    // ---- layer 0: K=64 over g, 4 chunks of 16 ----
    for (int c = 0; c < 4; ++c) {
        __syncthreads();
        for (int i = tid; i < 10240; i += 256) {
            int gl = i / 640, m = i - gl*640;
            int f = m / 10,  n = m - f*10;
            AL[gl*648 + m] = cw0[(f*64 + c*16 + gl)*10 + n];
        }
        __syncthreads();
        for (int kl = 0; kl < 16; ++kl) {
            float e[4];
            #pragma unroll
            for (int i = 0; i < 4; ++i) e[i] = EL[(rt*4+i)*65 + c*16 + kl];
            float a[20];
            #pragma unroll
            for (int j = 0; j < 20; ++j) a[j] = AL[kl*648 + ct*20 + j];
            #pragma unroll
            for (int i = 0; i < 4; ++i)
                #pragma unroll
                for (int j = 0; j < 20; ++j) acc[i][j] += e[i]*a[j];
        }
    }

    // epilogue for each layer: reduce T against E, write hL + hi_ws
    #define CIN_EPILOGUE(LIDX)                                                  \
    {                                                                           \
        __syncthreads(); /* all GEMM reads of hL/AL done before hL overwrite */ \
        _Pragma("unroll")                                                       \
        for (int i = 0; i < 4; ++i) {                                           \
            float e0 = EL[(rt*4+i)*65 + 2*ct];                                  \
            float e1 = EL[(rt*4+i)*65 + 2*ct + 1];                              \
            float pn[10];                                                       \
            _Pragma("unroll")                                                   \
            for (int n = 0; n < 10; ++n)                                        \
                pn[n] = e0*acc[i][n] + e1*acc[i][10+n];                         \
            _Pragma("unroll")                                                   \
            for (int n = 0; n < 10; ++n) {                                      \
                pn[n] += __shfl_xor(pn[n], 1, 64);                              \
                pn[n] += __shfl_xor(pn[n], 2, 64);                              \
                pn[n] += __shfl_xor(pn[n], 4, 64);                              \
                pn[n] += __shfl_xor(pn[n], 8, 64);                              \
                pn[n] += __shfl_xor(pn[n], 16, 64);                             \
            }                                                                   \
            float outv = pn[0];                                                 \
            _Pragma("unroll")                                                   \
            for (int n = 1; n < 10; ++n) if (ct == n) outv = pn[n];             \
            if (ct < 10) {                                                      \
                int r = rt*4 + i;                                               \
                hL[r*13 + ct] = outv;                                           \
                hi_ws[((size_t)(LIDX)*BD_ + rows0 + r)*10 + ct] = outv;         \
            }                                                                   \
        }                                                                       \
    }

    CIN_EPILOGUE(0)

    // ---- layers 1..4: K=10 over g ----
    for (int l = 1; l < 5; ++l) {
        const float* cw = (l==1) ? cw1 : (l==2) ? cw2 : (l==3) ? cw3 : cw4;
        __syncthreads();
        for (int i = tid; i < 6400; i += 256) {
            int gl = i / 640, m = i - gl*640;
            int f = m / 10,  n = m - f*10;
            AL[gl*648 + m] = cw[(f*10 + gl)*10 + n];
        }
        #pragma unroll
        for (int i = 0; i < 4; ++i)
            #pragma unroll
            for (int j = 0; j < 20; ++j) acc[i][j] = 0.f;
        __syncthreads();
        #pragma unroll
        for (int k = 0; k < 10; ++k) {
            float h[4];
            #pragma unroll
            for (int i = 0; i < 4; ++i) h[i] = hL[(rt*4+i)*13 + k];
            float a[20];
            #pragma unroll
            for (int j = 0; j < 20; ++j) a[j] = AL[k*648 + ct*20 + j];
            #pragma unroll
            for (int i = 0; i < 4; ++i)
                #pragma unroll
                for (int j = 0; j < 20; ++j) acc[i][j] += h[i]*a[j];
        }
        CIN_EPILOGUE(l)
    }
    #undef CIN_EPILOGUE
}

// ---------------------------------------------------------------------------
// k_combine: out[b] = sum_f liner*dw + sum cin*dw + sum_f rdnn + db + C
// ---------------------------------------------------------------------------
__global__ __launch_bounds__(64)
void k_combine(const float* __restrict__ liner,   // [ROWS]
               const float* __restrict__ rdnn,    // [ROWS]
               const float* __restrict__ hi_ws,   // [5][BD][10]
               const float* __restrict__ dw,      // [2162]
               const float* __restrict__ db,      // [1]
               const float* __restrict__ Cc,      // [1]
               float* __restrict__ out) {         // [B]
    int b = blockIdx.x, t = threadIdx.x;
    float s = liner[b*64+t]*dw[t] + rdnn[b*64+t];
    for (int i = t; i < 750; i += 64) {
        int ld = i / 10, n = i - ld*10;
        int l = ld / 15, d = ld - l*15;
        s += hi_ws[((size_t)l*BD_ + b*15 + d)*10 + n] * dw[64 + l*10 + n];
    }
    #pragma unroll
    for (int m = 1; m < 64; m <<= 1) s += __shfl_xor(s, m, 64);
    if (t == 0) out[b] = s + db[0] + Cc[0];
}

// ---------------------------------------------------------------------------
extern "C" void kernel_launch(void* const* d_in, const int* in_sizes, int n_in,
                              void* d_out, int out_size, void* d_ws, size_t ws_size,
                              hipStream_t stream) {
    const float* x    = (const float*)d_in[0];
    const float* embW = (const float*)d_in[1];
    const float* embB = (const float*)d_in[2];
    const float* linW = (const float*)d_in[3];
    const float* linB = (const float*)d_in[4];
    const float* W0   = (const float*)d_in[5];
    const float* b0   = (const float*)d_in[6];
    const float* W1   = (const float*)d_in[7];
    const float* b1   = (const float*)d_in[8];
    const float* W2   = (const float*)d_in[9];
    const float* bout = (const float*)d_in[10];
    const float* cw0  = (const float*)d_in[11];
    const float* cw1  = (const float*)d_in[12];
    const float* cw2  = (const float*)d_in[13];
    const float* cw3  = (const float*)d_in[14];
    const float* cw4  = (const float*)d_in[15];
    const float* dw   = (const float*)d_in[16];
    const float* db   = (const float*)d_in[17];

    float* ws = (float*)d_ws;
    float* emb_bfd = ws;                   // 1,966,080 floats
    float* emb_bdf = ws + 1966080;         // 1,966,080
    float* liner   = ws + 3932160;         //   131,072
    float* rdnn    = ws + 4063232;         //   131,072
    float* hi_ws   = ws + 4194304;         // 1,536,000
    float* v       = ws + 5730304;         //     8,192
    float* Cc      = ws + 5738496;         //         1  (total ~22.96 MB)
    float* out = (float*)d_out;

    k_prep<<<1, 256, 0, stream>>>(W2, bout, dw, v, Cc);
    k_emb<<<512, 256, 0, stream>>>(x, embW, embB, linW, linB, emb_bfd, emb_bdf, liner);
    k_dnn<<<1024, 256, 0, stream>>>(emb_bfd, W0, b0, W1, b1, v, rdnn);
    k_cin<<<960, 256, 0, stream>>>(emb_bdf, cw0, cw1, cw2, cw3, cw4, hi_ws);
    k_combine<<<2048, 64, 0, stream>>>(liner, rdnn, hi_ws, dw, db, Cc, out);
}